// Round 1
// baseline (35.879 us; speedup 1.0000x reference)
//
#include <hip/hip_runtime.h>
#include <math.h>

#define B_   4
#define C_   32
#define H_   128
#define W_   128
#define WIN_ 9
#define PAD_ 4
#define TW   16
#define TH   8
#define RW   (TW + WIN_ - 1)   /* 24 */
#define RH   (TH + WIN_ - 1)   /* 16 */
#define SP   36                /* padded pixel stride (floats): 144B -> 16B aligned, bank step 4 */
#define NPIX (RW * RH)         /* 384 */
#define NTHREADS 128

__global__ __launch_bounds__(NTHREADS)
void soft_shift_align(const float* __restrict__ q,
                      const float* __restrict__ k,
                      float* __restrict__ out) {
    __shared__ float lds[NPIX * SP];   // 384*36*4 = 55296 B

    const int tid = threadIdx.x;
    const int tx  = tid & (TW - 1);
    const int ty  = tid >> 4;
    const int x0  = blockIdx.x * TW;
    const int y0  = blockIdx.y * TH;
    const int b   = blockIdx.z;

    const float* kb = k + (size_t)b * C_ * H_ * W_;
    const float* qb = q + (size_t)b * C_ * H_ * W_;

    // ---- Stage normalized key region (with zero halo) into LDS ----
    for (int rp = tid; rp < NPIX; rp += NTHREADS) {
        const int ry = rp / RW;
        const int rx = rp - ry * RW;
        const int gy = y0 - PAD_ + ry;
        const int gx = x0 - PAD_ + rx;
        if (gy >= 0 && gy < H_ && gx >= 0 && gx < W_) {
            float v[C_];
            float ss = 0.f;
            const float* p = kb + gy * W_ + gx;
            #pragma unroll
            for (int c = 0; c < C_; ++c) {
                v[c] = p[c * (H_ * W_)];
                ss += v[c] * v[c];
            }
            const float inv = 1.f / fmaxf(sqrtf(ss), 1e-6f);
            #pragma unroll
            for (int i = 0; i < C_ / 4; ++i) {
                float4 t;
                t.x = v[4*i+0] * inv; t.y = v[4*i+1] * inv;
                t.z = v[4*i+2] * inv; t.w = v[4*i+3] * inv;
                *reinterpret_cast<float4*>(&lds[rp * SP + 4*i]) = t;
            }
        } else {
            const float4 z = {0.f, 0.f, 0.f, 0.f};
            #pragma unroll
            for (int i = 0; i < C_ / 4; ++i)
                *reinterpret_cast<float4*>(&lds[rp * SP + 4*i]) = z;
        }
    }

    // ---- Load + normalize this thread's query vector ----
    const int h = y0 + ty;
    const int w = x0 + tx;
    float qv[C_];
    {
        float ss = 0.f;
        const float* p = qb + h * W_ + w;
        #pragma unroll
        for (int c = 0; c < C_; ++c) { qv[c] = p[c * (H_ * W_)]; ss += qv[c] * qv[c]; }
        const float inv = 1.f / fmaxf(sqrtf(ss), 1e-6f);
        #pragma unroll
        for (int c = 0; c < C_; ++c) qv[c] *= inv;
    }

    __syncthreads();

    // ---- Online softmax over the 81 window positions ----
    float m = -INFINITY, l = 0.f;
    float acc[C_];
    #pragma unroll
    for (int c = 0; c < C_; ++c) acc[c] = 0.f;

    const float invT = 1.0f / 0.07f;

    for (int d = 0; d < WIN_ * WIN_; ++d) {
        const int dy = d / WIN_;
        const int dx = d - dy * WIN_;
        const int rp = (ty + dy) * RW + (tx + dx);
        const float* kp = &lds[rp * SP];

        float kv[C_];
        #pragma unroll
        for (int i = 0; i < C_ / 4; ++i) {
            const float4 t = *reinterpret_cast<const float4*>(kp + 4*i);
            kv[4*i+0] = t.x; kv[4*i+1] = t.y; kv[4*i+2] = t.z; kv[4*i+3] = t.w;
        }

        float dot = 0.f;
        #pragma unroll
        for (int c = 0; c < C_; ++c) dot += kv[c] * qv[c];
        const float sim = dot * invT;

        const float nm = fmaxf(m, sim);
        const float sc = __expf(m - nm);
        const float wg = __expf(sim - nm);
        l = l * sc + wg;
        #pragma unroll
        for (int c = 0; c < C_; ++c) acc[c] = acc[c] * sc + wg * kv[c];
        m = nm;
    }

    const float invl = 1.f / l;
    float* po = out + ((size_t)b * C_ * H_ + h) * W_ + w;
    #pragma unroll
    for (int c = 0; c < C_; ++c)
        po[c * (H_ * W_)] = acc[c] * invl;
}

extern "C" void kernel_launch(void* const* d_in, const int* in_sizes, int n_in,
                              void* d_out, int out_size, void* d_ws, size_t ws_size,
                              hipStream_t stream) {
    const float* q = (const float*)d_in[0];
    const float* k = (const float*)d_in[1];
    float* out = (float*)d_out;
    dim3 grid(W_ / TW, H_ / TH, B_);
    soft_shift_align<<<grid, NTHREADS, 0, stream>>>(q, k, out);
}

// Round 2
// 30.292 us; speedup vs baseline: 1.1844x; 1.1844x over previous
//
#include <hip/hip_runtime.h>
#include <hip/hip_fp16.h>
#include <math.h>

#define B_   4
#define C_   32
#define H_   128
#define W_   128
#define HW_  (H_ * W_)
#define WIN_ 9
#define PAD_ 4
#define TW   16
#define TH   8
#define RW   (TW + WIN_ - 1)   /* 24 */
#define RH   (TH + WIN_ - 1)   /* 16 */
#define NPIX (RW * RH)         /* 384 */
#define SPH2 20                /* pixel stride in half2 units: 80 B, 16B-aligned chunks */
#define NTHREADS 256           /* 2 threads per output pixel */

__global__ __launch_bounds__(NTHREADS, 2)
void soft_shift_align(const float* __restrict__ q,
                      const float* __restrict__ k,
                      float* __restrict__ out) {
    __shared__ __half2 lds[NPIX * SPH2];   // 384*80B = 30720 B

    const int tid = threadIdx.x;
    const int x0  = blockIdx.x * TW;
    const int y0  = blockIdx.y * TH;
    const int b   = blockIdx.z;

    const float* kb = k + (size_t)b * C_ * HW_;
    const float* qb = q + (size_t)b * C_ * HW_;

    // ---- Stage normalized key region (zero halo) into LDS as f16 ----
    for (int rp = tid; rp < NPIX; rp += NTHREADS) {
        const int ry = rp / RW;
        const int rx = rp - ry * RW;
        const int gy = y0 - PAD_ + ry;
        const int gx = x0 - PAD_ + rx;
        __half2* dst = &lds[rp * SPH2];
        if (gy >= 0 && gy < H_ && gx >= 0 && gx < W_) {
            float v[C_];
            float ss = 0.f;
            const float* p = kb + gy * W_ + gx;
            #pragma unroll
            for (int c = 0; c < C_; ++c) {
                v[c] = p[c * HW_];
                ss += v[c] * v[c];
            }
            const float inv = 1.f / fmaxf(sqrtf(ss), 1e-6f);
            #pragma unroll
            for (int i = 0; i < C_ / 2; ++i)
                dst[i] = __floats2half2_rn(v[2*i] * inv, v[2*i+1] * inv);
        } else {
            const __half2 z = __floats2half2_rn(0.f, 0.f);
            #pragma unroll
            for (int i = 0; i < C_ / 2; ++i) dst[i] = z;
        }
    }

    // ---- This thread: pixel px, channel-half hf (16 channels) ----
    const int px = tid >> 1;
    const int hf = tid & 1;
    const int tx = px & (TW - 1);
    const int ty = px >> 4;
    const int h  = y0 + ty;
    const int w  = x0 + tx;

    // Load + normalize query (split across the thread pair, combine via shfl)
    float qv[16];
    {
        float ss = 0.f;
        const float* p = qb + (hf * 16) * HW_ + h * W_ + w;
        #pragma unroll
        for (int j = 0; j < 16; ++j) { qv[j] = p[j * HW_]; ss += qv[j] * qv[j]; }
        ss += __shfl_xor(ss, 1, 64);
        const float inv = 1.f / fmaxf(sqrtf(ss), 1e-6f);
        #pragma unroll
        for (int j = 0; j < 16; ++j) qv[j] *= inv;
    }

    __syncthreads();

    // ---- Softmax-weighted aggregation, fixed shift (|sim| <= 1/T) ----
    const float invT = 1.0f / 0.07f;
    float acc[16];
    #pragma unroll
    for (int j = 0; j < 16; ++j) acc[j] = 0.f;
    float l = 0.f;

    for (int dy = 0; dy < WIN_; ++dy) {
        const int rowbase = (ty + dy) * RW + tx;
        #pragma unroll
        for (int dx = 0; dx < WIN_; ++dx) {
            const __half2* kp = &lds[(rowbase + dx) * SPH2 + hf * 8];

            // 32B = 2 x ds_read_b128
            float kv[16];
            #pragma unroll
            for (int i = 0; i < 2; ++i) {
                const float4 t = *reinterpret_cast<const float4*>(kp + i * 4);
                const __half2* hh = reinterpret_cast<const __half2*>(&t);
                #pragma unroll
                for (int u = 0; u < 4; ++u) {
                    const float2 f = __half22float2(hh[u]);
                    kv[i*8 + 2*u]     = f.x;
                    kv[i*8 + 2*u + 1] = f.y;
                }
            }

            // 4 independent partial chains for the dot
            float d0 = 0.f, d1 = 0.f, d2 = 0.f, d3 = 0.f;
            #pragma unroll
            for (int j = 0; j < 4; ++j) {
                d0 = fmaf(kv[j],      qv[j],      d0);
                d1 = fmaf(kv[j + 4],  qv[j + 4],  d1);
                d2 = fmaf(kv[j + 8],  qv[j + 8],  d2);
                d3 = fmaf(kv[j + 12], qv[j + 12], d3);
            }
            float dot = (d0 + d1) + (d2 + d3);
            dot += __shfl_xor(dot, 1, 64);

            const float wg = __expf(fmaf(dot, invT, -invT)); // exp(sim - 1/T), in (0,1]
            l += wg;
            #pragma unroll
            for (int j = 0; j < 16; ++j) acc[j] = fmaf(wg, kv[j], acc[j]);
        }
    }

    const float invl = 1.f / l;
    float* po = out + ((size_t)(b * C_ + hf * 16) * H_ + h) * W_ + w;
    #pragma unroll
    for (int j = 0; j < 16; ++j)
        po[j * HW_] = acc[j] * invl;
}

extern "C" void kernel_launch(void* const* d_in, const int* in_sizes, int n_in,
                              void* d_out, int out_size, void* d_ws, size_t ws_size,
                              hipStream_t stream) {
    const float* q = (const float*)d_in[0];
    const float* k = (const float*)d_in[1];
    float* out = (float*)d_out;
    dim3 grid(W_ / TW, H_ / TH, B_);
    soft_shift_align<<<grid, NTHREADS, 0, stream>>>(q, k, out);
}

// Round 3
// 29.000 us; speedup vs baseline: 1.2372x; 1.0445x over previous
//
#include <hip/hip_runtime.h>
#include <math.h>

#define B_   4
#define C_   32
#define H_   128
#define W_   128
#define HW_  (H_ * W_)
#define WIN_ 9
#define PAD_ 4
#define TW   8
#define TH   8
#define RW   (TW + WIN_ - 1)   /* 16 */
#define RH   (TH + WIN_ - 1)   /* 16 */
#define NPIX (RW * RH)         /* 256 */
#define NTHREADS 256           /* 4 threads per output pixel */

typedef _Float16 h2 __attribute__((ext_vector_type(2)));
typedef _Float16 h8 __attribute__((ext_vector_type(8)));

__device__ __forceinline__ float fdot2(h2 a, h2 b, float c) {
#if defined(__has_builtin) && __has_builtin(__builtin_amdgcn_fdot2)
    return __builtin_amdgcn_fdot2(a, b, c, false);
#else
    return c + (float)a[0] * (float)b[0] + (float)a[1] * (float)b[1];
#endif
}

__global__ __launch_bounds__(NTHREADS, 4)
void soft_shift_align(const float* __restrict__ q,
                      const float* __restrict__ k,
                      float* __restrict__ out) {
    __shared__ h8 lds[NPIX * 4];   // 256 px * 64 B = 16 KB

    const int tid = threadIdx.x;
    const int x0  = blockIdx.x * TW;
    const int y0  = blockIdx.y * TH;
    const int b   = blockIdx.z;

    const float* kb = k + (size_t)b * C_ * HW_;
    const float* qb = q + (size_t)b * C_ * HW_;

    // ---- Stage normalized key region (zero halo) into LDS as packed f16 ----
    {
        const int rp = tid;            // one pixel per thread (NPIX == NTHREADS)
        const int ry = rp >> 4;
        const int rx = rp & 15;
        const int gy = y0 - PAD_ + ry;
        const int gx = x0 - PAD_ + rx;
        if (gy >= 0 && gy < H_ && gx >= 0 && gx < W_) {
            float v[C_];
            float ss = 0.f;
            const float* p = kb + gy * W_ + gx;
            #pragma unroll
            for (int c = 0; c < C_; ++c) { v[c] = p[c * HW_]; ss += v[c] * v[c]; }
            const float inv = 1.f / fmaxf(sqrtf(ss), 1e-6f);
            #pragma unroll
            for (int i = 0; i < 4; ++i) {
                h8 o;
                #pragma unroll
                for (int j = 0; j < 8; ++j) o[j] = (_Float16)(v[i * 8 + j] * inv);
                lds[rp * 4 + i] = o;
            }
        } else {
            const h8 z = (h8)(_Float16)0.f;
            #pragma unroll
            for (int i = 0; i < 4; ++i) lds[rp * 4 + i] = z;
        }
    }

    // ---- This thread: pixel px, channel-quarter sub (8 channels) ----
    const int px  = tid >> 2;
    const int sub = tid & 3;
    const int tx  = px & (TW - 1);
    const int ty  = px >> 3;
    const int h   = y0 + ty;
    const int w   = x0 + tx;

    // Load + normalize query (split across 4 threads, combine via shfl)
    h2 qv2[4];
    {
        float qv[8];
        float ss = 0.f;
        const float* p = qb + (sub * 8) * HW_ + h * W_ + w;
        #pragma unroll
        for (int j = 0; j < 8; ++j) { qv[j] = p[j * HW_]; ss += qv[j] * qv[j]; }
        ss += __shfl_xor(ss, 1, 64);
        ss += __shfl_xor(ss, 2, 64);
        const float inv = 1.f / fmaxf(sqrtf(ss), 1e-6f);
        #pragma unroll
        for (int u = 0; u < 4; ++u) {
            qv2[u][0] = (_Float16)(qv[2 * u]     * inv);
            qv2[u][1] = (_Float16)(qv[2 * u + 1] * inv);
        }
    }

    __syncthreads();

    // ---- Softmax-weighted aggregation, fixed shift (|sim| <= 1/T) ----
    const float invT = 1.0f / 0.07f;
    h2 acc[4];
    #pragma unroll
    for (int u = 0; u < 4; ++u) acc[u] = (h2)(_Float16)0.f;
    float l = 0.f;

    for (int dy = 0; dy < WIN_; ++dy) {
        const int rowbase = ((ty + dy) * RW + tx) * 4 + sub;
        #pragma unroll
        for (int dx = 0; dx < WIN_; ++dx) {
            const h8 kv = lds[rowbase + dx * 4];   // one ds_read_b128
            h2 kv2[4];
            kv2[0] = __builtin_shufflevector(kv, kv, 0, 1);
            kv2[1] = __builtin_shufflevector(kv, kv, 2, 3);
            kv2[2] = __builtin_shufflevector(kv, kv, 4, 5);
            kv2[3] = __builtin_shufflevector(kv, kv, 6, 7);

            float dA = fdot2(kv2[0], qv2[0], 0.f);
            dA = fdot2(kv2[1], qv2[1], dA);
            float dB = fdot2(kv2[2], qv2[2], 0.f);
            dB = fdot2(kv2[3], qv2[3], dB);
            float dot = dA + dB;
            dot += __shfl_xor(dot, 1, 64);
            dot += __shfl_xor(dot, 2, 64);

            const float wg = __expf(fmaf(dot, invT, -invT));  // exp(sim - 1/T) in (0,1]
            l += wg;
            const _Float16 wh = (_Float16)wg;
            const h2 wgh = {wh, wh};
            #pragma unroll
            for (int u = 0; u < 4; ++u) acc[u] = wgh * kv2[u] + acc[u];  // v_pk_fma_f16
        }
    }

    const float invl = 1.f / l;
    float* po = out + ((size_t)(b * C_ + sub * 8) * H_ + h) * W_ + w;
    #pragma unroll
    for (int u = 0; u < 4; ++u) {
        po[(2 * u)     * HW_] = (float)acc[u][0] * invl;
        po[(2 * u + 1) * HW_] = (float)acc[u][1] * invl;
    }
}

extern "C" void kernel_launch(void* const* d_in, const int* in_sizes, int n_in,
                              void* d_out, int out_size, void* d_ws, size_t ws_size,
                              hipStream_t stream) {
    const float* q = (const float*)d_in[0];
    const float* k = (const float*)d_in[1];
    float* out = (float*)d_out;
    dim3 grid(W_ / TW, H_ / TH, B_);
    soft_shift_align<<<grid, NTHREADS, 0, stream>>>(q, k, out);
}

// Round 5
// 25.869 us; speedup vs baseline: 1.3869x; 1.1210x over previous
//
#include <hip/hip_runtime.h>
#include <math.h>

#define B_   4
#define C_   32
#define H_   128
#define W_   128
#define HW_  (H_ * W_)
#define WIN_ 9
#define PAD_ 4
#define TW   16
#define TH   8
#define RW   (TW + WIN_ - 1)   /* 24 */
#define RH   (TH + WIN_ - 1)   /* 16 */
#define NPIX (RW * RH)         /* 384 */
#define SPC  5                 /* pixel stride in 16B chunks = 80B, coprime with 8 bank-groups */
#define NTHREADS 512           /* 4 threads per output pixel, 128 px/block */

typedef _Float16 h2 __attribute__((ext_vector_type(2)));
typedef _Float16 h8 __attribute__((ext_vector_type(8)));

union h8v { h8 v; h2 h[4]; };

__device__ __forceinline__ float fdot2(h2 a, h2 b, float c) {
    return __builtin_amdgcn_fdot2(a, b, c, false);
}

__device__ __forceinline__ h2 shfl_xor_h2(h2 v, int mask) {
    union { h2 h; int i; } u; u.h = v;
    u.i = __shfl_xor(u.i, mask, 64);
    return u.h;
}

__global__ __launch_bounds__(NTHREADS, 4)
void soft_shift_align(const float* __restrict__ q,
                      const float* __restrict__ k,
                      float* __restrict__ out) {
    __shared__ h8 lds[NPIX * SPC];   // 384 * 80 B = 30720 B

    const int tid = threadIdx.x;
    const int x0  = blockIdx.x * TW;
    const int y0  = blockIdx.y * TH;
    const int b   = blockIdx.z;

    const float* kb = k + (size_t)b * C_ * HW_;
    const float* qb = q + (size_t)b * C_ * HW_;

    // ---- Stage normalized key region (zero halo) into LDS as packed f16 ----
    if (tid < NPIX) {
        const int ry = tid / RW;
        const int rx = tid - ry * RW;
        const int gy = y0 - PAD_ + ry;
        const int gx = x0 - PAD_ + rx;
        h8 o[4];
        if (gy >= 0 && gy < H_ && gx >= 0 && gx < W_) {
            float v[C_];
            float ss = 0.f;
            const float* p = kb + gy * W_ + gx;
            #pragma unroll
            for (int c = 0; c < C_; ++c) { v[c] = p[c * HW_]; ss += v[c] * v[c]; }
            const float inv = 1.f / fmaxf(sqrtf(ss), 1e-6f);
            #pragma unroll
            for (int i = 0; i < 4; ++i)
                #pragma unroll
                for (int j = 0; j < 8; ++j) o[i][j] = (_Float16)(v[i * 8 + j] * inv);
        } else {
            #pragma unroll
            for (int i = 0; i < 4; ++i) o[i] = (h8)(_Float16)0.f;
        }
        #pragma unroll
        for (int i = 0; i < 4; ++i) lds[tid * SPC + i] = o[i];
    }

    // ---- This thread: pixel px, position-subset sub (p = 4i + sub) ----
    const int px  = tid >> 2;
    const int sub = tid & 3;
    const int tx  = px & (TW - 1);
    const int ty  = px >> 4;
    const int h   = y0 + ty;
    const int w   = x0 + tx;

    // Full normalized query in registers (all 32 ch per thread; L1/L2-served)
    h2 qv[16];
    {
        float v[C_];
        float ss = 0.f;
        const float* p = qb + h * W_ + w;
        #pragma unroll
        for (int c = 0; c < C_; ++c) { v[c] = p[c * HW_]; ss += v[c] * v[c]; }
        const float inv = 1.f / fmaxf(sqrtf(ss), 1e-6f);
        #pragma unroll
        for (int u = 0; u < 16; ++u) {
            qv[u][0] = (_Float16)(v[2*u]     * inv);
            qv[u][1] = (_Float16)(v[2*u + 1] * inv);
        }
    }

    __syncthreads();

    // ---- Softmax-weighted aggregation over this thread's ~20 positions ----
    const float invT = 1.0f / 0.07f;
    h2 acc[16];
    #pragma unroll
    for (int u = 0; u < 16; ++u) acc[u] = (h2)(_Float16)0.f;
    float l = 0.f;

    #pragma unroll
    for (int i = 0; i < 21; ++i) {
        const int p = i * 4 + sub;
        if (p <= 80) {                       // only i==20 is partial (sub!=0 idle)
            const int dy = (p * 57) >> 9;    // floor(p/9) for p in [0,80]
            const int dx = p - dy * 9;
            const h8* kp = &lds[((ty + dy) * RW + (tx + dx)) * SPC];
            h8v kk[4];
            kk[0].v = kp[0]; kk[1].v = kp[1]; kk[2].v = kp[2]; kk[3].v = kp[3];

            float dA = 0.f, dB = 0.f, dC = 0.f, dD = 0.f;
            #pragma unroll
            for (int u = 0; u < 4; ++u) {
                dA = fdot2(kk[0].h[u], qv[u],      dA);
                dB = fdot2(kk[1].h[u], qv[4 + u],  dB);
                dC = fdot2(kk[2].h[u], qv[8 + u],  dC);
                dD = fdot2(kk[3].h[u], qv[12 + u], dD);
            }
            const float dot = (dA + dB) + (dC + dD);
            const float wg = __expf(fmaf(dot, invT, -invT));  // exp(sim - 1/T) in (0,1]
            l += wg;
            const _Float16 wh = (_Float16)wg;
            const h2 wgh = {wh, wh};
            #pragma unroll
            for (int u = 0; u < 4; ++u) {
                acc[u]      = wgh * kk[0].h[u] + acc[u];       // v_pk_fma_f16
                acc[4 + u]  = wgh * kk[1].h[u] + acc[4 + u];
                acc[8 + u]  = wgh * kk[2].h[u] + acc[8 + u];
                acc[12 + u] = wgh * kk[3].h[u] + acc[12 + u];
            }
        }
    }

    // ---- Combine the 4 partial (l, acc) across the pixel's thread quad (xor 1,2 -> DPP) ----
    l += __shfl_xor(l, 1, 64);
    #pragma unroll
    for (int u = 0; u < 16; ++u) acc[u] = acc[u] + shfl_xor_h2(acc[u], 1);
    l += __shfl_xor(l, 2, 64);
    #pragma unroll
    for (int u = 0; u < 16; ++u) acc[u] = acc[u] + shfl_xor_h2(acc[u], 2);

    // ---- Each thread writes its 8 channels ----
    const float invl = 1.f / l;
    float* po = out + ((size_t)(b * C_ + sub * 8) * H_ + h) * W_ + w;
    #pragma unroll
    for (int j = 0; j < 8; ++j) {
        const int u = sub * 4 + (j >> 1);
        po[j * HW_] = (float)acc[u][j & 1] * invl;
    }
}

extern "C" void kernel_launch(void* const* d_in, const int* in_sizes, int n_in,
                              void* d_out, int out_size, void* d_ws, size_t ws_size,
                              hipStream_t stream) {
    const float* q = (const float*)d_in[0];
    const float* k = (const float*)d_in[1];
    float* out = (float*)d_out;
    dim3 grid(W_ / TW, H_ / TH, B_);
    soft_shift_align<<<grid, NTHREADS, 0, stream>>>(q, k, out);
}